// Round 1
// 2235.177 us; speedup vs baseline: 1.0553x; 1.0553x over previous
//
#include <hip/hip_runtime.h>
#include <hip/hip_bf16.h>

#define DIM 64

typedef _Float16 f16;
typedef _Float16 half8 __attribute__((ext_vector_type(8)));
typedef _Float16 half4 __attribute__((ext_vector_type(4)));

// ---------------- dtype detection ----------------
// flags: [0]=u_f32 [1]=i_f32 [2]=w_f32 [3]=ui_i64 [4]=ii_i64
__global__ void k_detect(const unsigned short* __restrict__ ue,
                         const unsigned short* __restrict__ ie,
                         const unsigned short* __restrict__ we,
                         const unsigned int* __restrict__ uidx,
                         const unsigned int* __restrict__ iidx,
                         int* __restrict__ flags) {
  if (threadIdx.x != 0 || blockIdx.x != 0) return;
  auto isf32 = [](const unsigned short* p) {
    for (int i = 0; i < 256; ++i)
      if (((p[i] >> 7) & 0xFF) >= 142) return 1;  // f32 mantissa garbage as bf16
    return 0;
  };
  auto is64 = [](const unsigned int* p) {
    for (int i = 0; i < 64; ++i)
      if (p[2 * i + 1] != 0u) return 0;
    return 1;
  };
  flags[0] = isf32(ue);
  flags[1] = isf32(ie);
  flags[2] = isf32(we);
  flags[3] = is64(uidx);
  flags[4] = is64(iidx);
}

__device__ __forceinline__ int load_idx(const int* p, int e, int f64) {
  return f64 ? (int)((const long long*)p)[e] : p[e];
}

// ---------------- degree ----------------
__global__ void k_degree(const int* __restrict__ ui, const int* __restrict__ ii,
                         const int* __restrict__ flags,
                         int* __restrict__ deg, int E, int NU) {
  int e = blockIdx.x * blockDim.x + threadIdx.x;
  if (e >= E) return;
  atomicAdd(&deg[load_idx(ui, e, flags[3])], 1);
  atomicAdd(&deg[NU + load_idx(ii, e, flags[4])], 1);
}

__global__ void k_dinv(const int* __restrict__ deg, float* __restrict__ dinv, int N) {
  int i = blockIdx.x * blockDim.x + threadIdx.x;
  if (i < N) dinv[i] = rsqrtf((float)deg[i] + 1e-10f);
}

// ---------------- prescale: xs[r][d] = fp16(dinv[r] * x[r][d]) ----------------
// One thread per 4 dims. Removes per-edge dinv gather + dtype branches from the
// hot gather loop. (deg==0 rows may overflow fp16 but are never gathered.)
__global__ void k_prescale(const void* __restrict__ xA, const void* __restrict__ xB,
                           int split, const float* __restrict__ dinv,
                           const int* __restrict__ flags,
                           f16* __restrict__ xs, int N) {
  int i = blockIdx.x * blockDim.x + threadIdx.x;  // quad index
  int total = N * (DIM / 4);
  if (i >= total) return;
  int r = i >> 4;      // 16 quads per row
  int q = i & 15;
  const float dv = dinv[r];
  const int f = (r < split) ? flags[0] : flags[1];
  const void* base = (r < split) ? xA : xB;
  size_t o = (size_t)(r < split ? r : r - split) * DIM + (q << 2);
  float v0, v1, v2, v3;
  if (f) {
    float4 x4 = *(const float4*)((const float*)base + o);
    v0 = x4.x; v1 = x4.y; v2 = x4.z; v3 = x4.w;
  } else {
    ushort4 x4 = *(const ushort4*)((const unsigned short*)base + o);
    v0 = __uint_as_float((unsigned)x4.x << 16);
    v1 = __uint_as_float((unsigned)x4.y << 16);
    v2 = __uint_as_float((unsigned)x4.z << 16);
    v3 = __uint_as_float((unsigned)x4.w << 16);
  }
  half4 h;
  h[0] = (f16)(v0 * dv); h[1] = (f16)(v1 * dv);
  h[2] = (f16)(v2 * dv); h[3] = (f16)(v3 * dv);
  *(half4*)(xs + (size_t)r * DIM + (q << 2)) = h;
}

// ---------------- exclusive scan over PADDED degrees (3-phase) ----------------
// Row starts padded to multiples of 4 ints so cols can be int4-loaded.
__global__ void k_scan1(const int* __restrict__ deg, int* __restrict__ bsum, int N) {
  __shared__ int s[256];
  int i = blockIdx.x * 256 + threadIdx.x;
  s[threadIdx.x] = (i < N) ? ((deg[i] + 3) & ~3) : 0;
  __syncthreads();
  for (int off = 128; off > 0; off >>= 1) {
    if (threadIdx.x < off) s[threadIdx.x] += s[threadIdx.x + off];
    __syncthreads();
  }
  if (threadIdx.x == 0) bsum[blockIdx.x] = s[0];
}

__global__ void k_scan2(int* __restrict__ bsum, int nb) {
  __shared__ int s[1024];
  int t = threadIdx.x;
  int v = (t < nb) ? bsum[t] : 0;
  s[t] = v;
  __syncthreads();
  for (int off = 1; off < 1024; off <<= 1) {
    int tmp = (t >= off) ? s[t - off] : 0;
    __syncthreads();
    s[t] += tmp;
    __syncthreads();
  }
  if (t < nb) bsum[t] = s[t] - v;  // exclusive
}

__global__ void k_scan3(const int* __restrict__ deg, const int* __restrict__ bsum,
                        int* __restrict__ row_ptr, int N) {
  __shared__ int s[256];
  int t = threadIdx.x;
  int i = blockIdx.x * 256 + t;
  int v = (i < N) ? ((deg[i] + 3) & ~3) : 0;
  s[t] = v;
  __syncthreads();
  for (int off = 1; off < 256; off <<= 1) {
    int tmp = (t >= off) ? s[t - off] : 0;
    __syncthreads();
    s[t] += tmp;
    __syncthreads();
  }
  if (i < N) row_ptr[i] = bsum[blockIdx.x] + s[t] - v;
}

// ---------------- scatter edges into CSR (cols only) ----------------
__global__ void k_scatter(const int* __restrict__ ui, const int* __restrict__ ii,
                          const int* __restrict__ flags, const int* __restrict__ row_ptr,
                          int* __restrict__ cnt, int* __restrict__ cols, int E, int NU) {
  int e = blockIdx.x * blockDim.x + threadIdx.x;
  if (e >= E) return;
  int u = load_idx(ui, e, flags[3]);
  int it = NU + load_idx(ii, e, flags[4]);
  cols[row_ptr[u] + atomicAdd(&cnt[u], 1)] = it;
  cols[row_ptr[it] + atomicAdd(&cnt[it], 1)] = u;
}

// ---------------- fused SpMM + Linear + ReLU ----------------
// gsrc is pre-scaled fp16 (dinv[c]*feat[c]); gather is pure sums.
// Wave layout: lane = 8*g + t; group g handles 4 contiguous edges per iter
// via one int4 cols load; lane t loads dims 8t..8t+7 as one 16B load.
// => 32 edges in flight per iteration, 5 vmem instructions.
// MODE 0: gsrc=xs   -> houts = h1*dinv[r]
// MODE 1: gsrc=h1s  -> houts = h2*dinv[r]
// MODE 2: gsrc=h2s  -> fout = (x + h1 + h2 + h3)/4 (h1,h2 rebuilt via sqrt(deg))
template <int MODE>
__global__ __launch_bounds__(256, 8) void k_layer(
    const int* __restrict__ row_ptr, const int* __restrict__ deg,
    const int* __restrict__ cols, const f16* __restrict__ gsrc,
    const void* __restrict__ xA, const void* __restrict__ xB, int split,
    const void* __restrict__ Wbase, int layer, const int* __restrict__ flags,
    const f16* __restrict__ h1s, const f16* __restrict__ h2s,
    f16* __restrict__ houts, float* __restrict__ fout, int N) {
  const int fw = flags[2];
  __shared__ float Wt[64 * 64];  // Wt[k*64 + d] = W[l][d][k]
  for (int i = threadIdx.x; i < 64 * 64; i += 256) {
    float wv = fw ? ((const float*)Wbase)[layer * 4096 + i]
                  : __bfloat162float(((const __hip_bfloat16*)Wbase)[layer * 4096 + i]);
    int d = i >> 6, k = i & 63;
    Wt[(k << 6) + d] = wv;
  }
  __syncthreads();

  const int wave = threadIdx.x >> 6;
  const int lane = threadIdx.x & 63;
  const int g = lane >> 3;  // edge-slot group 0..7
  const int t = lane & 7;   // dim chunk: dims 8t..8t+7
  const int stride = gridDim.x * 4;
  const f16* pb = gsrc + (t << 3);
  const int fu = flags[0], fi = flags[1];

  for (int r = blockIdx.x * 4 + wave; r < N; r += stride) {
    const int start = row_ptr[r];  // multiple of 4 (padded CSR)
    const int dr = deg[r];
    const int end = start + dr;
    const float dinv_r = rsqrtf((float)dr + 1e-10f);

    float sv[8] = {0.f, 0.f, 0.f, 0.f, 0.f, 0.f, 0.f, 0.f};

    int e = start;
    for (; e + 32 <= end; e += 32) {
      int4 c4 = *(const int4*)(cols + e + (g << 2));  // 16B aligned
      half8 v0 = *(const half8*)(pb + ((size_t)c4.x << 6));
      half8 v1 = *(const half8*)(pb + ((size_t)c4.y << 6));
      half8 v2 = *(const half8*)(pb + ((size_t)c4.z << 6));
      half8 v3 = *(const half8*)(pb + ((size_t)c4.w << 6));
#pragma unroll
      for (int k = 0; k < 8; ++k)
        sv[k] += ((float)v0[k] + (float)v1[k]) + ((float)v2[k] + (float)v3[k]);
    }
    int rem = end - e;
    if (rem > 0) {
      // cols allocation is padded; values beyond `end` are loaded but never used
      int4 c4 = *(const int4*)(cols + e + (g << 2));
      int k0 = g << 2;
#pragma unroll
      for (int j = 0; j < 4; ++j) {
        int cj = (j == 0) ? c4.x : (j == 1) ? c4.y : (j == 2) ? c4.z : c4.w;
        if (k0 + j < rem) {
          half8 v = *(const half8*)(pb + ((size_t)cj << 6));
#pragma unroll
          for (int k = 0; k < 8; ++k) sv[k] += (float)v[k];
        }
      }
    }

    // reduce across the 8 edge groups (lanes with same t), then scale by dinv[r]
#pragma unroll
    for (int k = 0; k < 8; ++k) {
      float s = sv[k];
      s += __shfl_xor(s, 8);
      s += __shfl_xor(s, 16);
      s += __shfl_xor(s, 32);
      sv[k] = s * dinv_r;
    }

    // lin[d] = sum_k agg[k] * W[d][k]; dim k lives in lane (k>>3), elem (k&7)
    float lin = 0.f;
#pragma unroll
    for (int k = 0; k < 64; ++k) {
      float a = __shfl(sv[k & 7], k >> 3);
      lin += a * Wt[(k << 6) + lane];
    }
    float hn = lin > 0.f ? lin : 0.f;

    size_t o = (size_t)r * DIM + lane;
    if constexpr (MODE == 2) {
      float xr;
      if (r < split) {
        size_t ox = (size_t)r * DIM + lane;
        xr = fu ? ((const float*)xA)[ox]
                : __bfloat162float(((const __hip_bfloat16*)xA)[ox]);
      } else {
        size_t ox = (size_t)(r - split) * DIM + lane;
        xr = fi ? ((const float*)xB)[ox]
                : __bfloat162float(((const __hip_bfloat16*)xB)[ox]);
      }
      float sr = sqrtf((float)dr + 1e-10f);  // un-scale stored h1s/h2s
      float h1v = (float)h1s[o] * sr;
      float h2v = (float)h2s[o] * sr;
      fout[o] = (xr + h1v + h2v + hn) * 0.25f;  // FLOAT32 output
    } else {
      houts[o] = (f16)(hn * dinv_r);
    }
  }
}

extern "C" void kernel_launch(void* const* d_in, const int* in_sizes, int n_in,
                              void* d_out, int out_size, void* d_ws, size_t ws_size,
                              hipStream_t stream) {
  const void* user_e = d_in[0];
  const void* item_e = d_in[1];
  const void* W = d_in[2];
  const int* ui = (const int*)d_in[3];
  const int* ii = (const int*)d_in[4];

  const int NU = in_sizes[0] / DIM;
  const int NI = in_sizes[1] / DIM;
  const int N = NU + NI;
  const int E = in_sizes[3];
  float* out = (float*)d_out;  // OUTPUT IS FLOAT32

  // Workspace ~86 MB (N=150k, E=3M)
  auto align = [](size_t x) { return (x + 255) & ~(size_t)255; };
  char* w = (char*)d_ws;
  size_t off = 0;
  int* deg = (int*)(w + off);      off += align((size_t)N * 4);
  int* cnt = (int*)(w + off);      off += align((size_t)N * 4);
  int* bsum = (int*)(w + off);     off += align((size_t)4096 * 4);
  int* flags = (int*)(w + off);    off += align(256);
  size_t meta_zero_bytes = off;
  int* row_ptr = (int*)(w + off);  off += align((size_t)N * 4);
  float* dinv = (float*)(w + off); off += align((size_t)N * 4);
  // padded CSR: sum(ceil(deg/4)*4) <= 2E+3N, plus 64-int tail pad for int4 reads
  int* cols = (int*)(w + off);     off += align(((size_t)2 * E + 4 * (size_t)N + 64) * 4);
  f16* xs = (f16*)(w + off);       off += align((size_t)N * DIM * 2);
  f16* h1s = (f16*)(w + off);      off += align((size_t)N * DIM * 2);
  f16* h2s = (f16*)(w + off);      off += align((size_t)N * DIM * 2);
  (void)ws_size;

  hipMemsetAsync(d_ws, 0, meta_zero_bytes, stream);

  k_detect<<<1, 64, 0, stream>>>((const unsigned short*)user_e,
                                 (const unsigned short*)item_e,
                                 (const unsigned short*)W,
                                 (const unsigned int*)ui,
                                 (const unsigned int*)ii, flags);

  const int TPB = 256;
  k_degree<<<(E + TPB - 1) / TPB, TPB, 0, stream>>>(ui, ii, flags, deg, E, NU);
  k_dinv<<<(N + TPB - 1) / TPB, TPB, 0, stream>>>(deg, dinv, N);
  k_prescale<<<(N * (DIM / 4) + TPB - 1) / TPB, TPB, 0, stream>>>(
      user_e, item_e, NU, dinv, flags, xs, N);

  int nb = (N + 255) / 256;  // 586 for N=150000, must be <= 1024
  k_scan1<<<nb, 256, 0, stream>>>(deg, bsum, N);
  k_scan2<<<1, 1024, 0, stream>>>(bsum, nb);
  k_scan3<<<nb, 256, 0, stream>>>(deg, bsum, row_ptr, N);

  k_scatter<<<(E + TPB - 1) / TPB, TPB, 0, stream>>>(ui, ii, flags, row_ptr, cnt,
                                                     cols, E, NU);

  const int LGRID = 2048;  // 8 blocks/CU, exact residency at 64 VGPR
  k_layer<0><<<LGRID, 256, 0, stream>>>(row_ptr, deg, cols, xs, user_e, item_e, NU,
                                        W, 0, flags, nullptr, nullptr, h1s, nullptr, N);
  k_layer<1><<<LGRID, 256, 0, stream>>>(row_ptr, deg, cols, h1s, user_e, item_e, NU,
                                        W, 1, flags, nullptr, nullptr, h2s, nullptr, N);
  k_layer<2><<<LGRID, 256, 0, stream>>>(row_ptr, deg, cols, h2s, user_e, item_e, NU,
                                        W, 2, flags, h1s, h2s, nullptr, out, N);
}

// Round 2
// 1463.681 us; speedup vs baseline: 1.6116x; 1.5271x over previous
//
#include <hip/hip_runtime.h>
#include <hip/hip_bf16.h>

#define DIM 64

typedef _Float16 f16;
typedef _Float16 half8 __attribute__((ext_vector_type(8)));
typedef _Float16 half4 __attribute__((ext_vector_type(4)));

// ---------------- dtype detection ----------------
// flags: [0]=u_f32 [1]=i_f32 [2]=w_f32 [3]=ui_i64 [4]=ii_i64
__global__ void k_detect(const unsigned short* __restrict__ ue,
                         const unsigned short* __restrict__ ie,
                         const unsigned short* __restrict__ we,
                         const unsigned int* __restrict__ uidx,
                         const unsigned int* __restrict__ iidx,
                         int* __restrict__ flags) {
  if (threadIdx.x != 0 || blockIdx.x != 0) return;
  auto isf32 = [](const unsigned short* p) {
    for (int i = 0; i < 256; ++i)
      if (((p[i] >> 7) & 0xFF) >= 142) return 1;  // f32 mantissa garbage as bf16
    return 0;
  };
  auto is64 = [](const unsigned int* p) {
    for (int i = 0; i < 64; ++i)
      if (p[2 * i + 1] != 0u) return 0;
    return 1;
  };
  flags[0] = isf32(ue);
  flags[1] = isf32(ie);
  flags[2] = isf32(we);
  flags[3] = is64(uidx);
  flags[4] = is64(iidx);
}

__device__ __forceinline__ int load_idx(const int* p, int e, int f64) {
  return f64 ? (int)((const long long*)p)[e] : p[e];
}

// ---------------- degree ----------------
__global__ void k_degree(const int* __restrict__ ui, const int* __restrict__ ii,
                         const int* __restrict__ flags,
                         int* __restrict__ deg, int E, int NU) {
  int e = blockIdx.x * blockDim.x + threadIdx.x;
  if (e >= E) return;
  atomicAdd(&deg[load_idx(ui, e, flags[3])], 1);
  atomicAdd(&deg[NU + load_idx(ii, e, flags[4])], 1);
}

__global__ void k_dinv(const int* __restrict__ deg, float* __restrict__ dinv, int N) {
  int i = blockIdx.x * blockDim.x + threadIdx.x;
  if (i < N) dinv[i] = rsqrtf((float)deg[i] + 1e-10f);
}

// ---------------- prescale: xs[r][d] = fp16(dinv[r] * x[r][d]) ----------------
__global__ void k_prescale(const void* __restrict__ xA, const void* __restrict__ xB,
                           int split, const float* __restrict__ dinv,
                           const int* __restrict__ flags,
                           f16* __restrict__ xs, int N) {
  int i = blockIdx.x * blockDim.x + threadIdx.x;  // quad index
  int total = N * (DIM / 4);
  if (i >= total) return;
  int r = i >> 4;      // 16 quads per row
  int q = i & 15;
  const float dv = dinv[r];
  const int f = (r < split) ? flags[0] : flags[1];
  const void* base = (r < split) ? xA : xB;
  size_t o = (size_t)(r < split ? r : r - split) * DIM + (q << 2);
  float v0, v1, v2, v3;
  if (f) {
    float4 x4 = *(const float4*)((const float*)base + o);
    v0 = x4.x; v1 = x4.y; v2 = x4.z; v3 = x4.w;
  } else {
    ushort4 x4 = *(const ushort4*)((const unsigned short*)base + o);
    v0 = __uint_as_float((unsigned)x4.x << 16);
    v1 = __uint_as_float((unsigned)x4.y << 16);
    v2 = __uint_as_float((unsigned)x4.z << 16);
    v3 = __uint_as_float((unsigned)x4.w << 16);
  }
  half4 h;
  h[0] = (f16)(v0 * dv); h[1] = (f16)(v1 * dv);
  h[2] = (f16)(v2 * dv); h[3] = (f16)(v3 * dv);
  *(half4*)(xs + (size_t)r * DIM + (q << 2)) = h;
}

// ---------------- exclusive scan over PADDED degrees (3-phase) ----------------
__global__ void k_scan1(const int* __restrict__ deg, int* __restrict__ bsum, int N) {
  __shared__ int s[256];
  int i = blockIdx.x * 256 + threadIdx.x;
  s[threadIdx.x] = (i < N) ? ((deg[i] + 3) & ~3) : 0;
  __syncthreads();
  for (int off = 128; off > 0; off >>= 1) {
    if (threadIdx.x < off) s[threadIdx.x] += s[threadIdx.x + off];
    __syncthreads();
  }
  if (threadIdx.x == 0) bsum[blockIdx.x] = s[0];
}

__global__ void k_scan2(int* __restrict__ bsum, int nb) {
  __shared__ int s[1024];
  int t = threadIdx.x;
  int v = (t < nb) ? bsum[t] : 0;
  s[t] = v;
  __syncthreads();
  for (int off = 1; off < 1024; off <<= 1) {
    int tmp = (t >= off) ? s[t - off] : 0;
    __syncthreads();
    s[t] += tmp;
    __syncthreads();
  }
  if (t < nb) bsum[t] = s[t] - v;  // exclusive
}

__global__ void k_scan3(const int* __restrict__ deg, const int* __restrict__ bsum,
                        int* __restrict__ row_ptr, int N) {
  __shared__ int s[256];
  int t = threadIdx.x;
  int i = blockIdx.x * 256 + t;
  int v = (i < N) ? ((deg[i] + 3) & ~3) : 0;
  s[t] = v;
  __syncthreads();
  for (int off = 1; off < 256; off <<= 1) {
    int tmp = (t >= off) ? s[t - off] : 0;
    __syncthreads();
    s[t] += tmp;
    __syncthreads();
  }
  if (i < N) row_ptr[i] = bsum[blockIdx.x] + s[t] - v;
}

// ---------------- scatter edges into CSR (cols only) ----------------
__global__ void k_scatter(const int* __restrict__ ui, const int* __restrict__ ii,
                          const int* __restrict__ flags, const int* __restrict__ row_ptr,
                          int* __restrict__ cnt, int* __restrict__ cols, int E, int NU) {
  int e = blockIdx.x * blockDim.x + threadIdx.x;
  if (e >= E) return;
  int u = load_idx(ui, e, flags[3]);
  int it = NU + load_idx(ii, e, flags[4]);
  cols[row_ptr[u] + atomicAdd(&cnt[u], 1)] = it;
  cols[row_ptr[it] + atomicAdd(&cnt[it], 1)] = u;
}

// ---------------- fused SpMM + Linear + ReLU ----------------
// gsrc is pre-scaled fp16 (dinv[c]*feat[c]); gather is pure sums.
// Wave layout: lane = 8*g + t; group g handles 4 contiguous edges per iter
// via one int4 cols load; lane t loads dims 8t..8t+7 as one 16B load.
// => 32 edges in flight per iteration, 5 vmem instructions.
// __launch_bounds__(256,4): 128-VGPR budget. (256,8) forced a 64-VGPR cap and
// SPILLED the loop working set -> 755 MB scratch writes / +1.2 GB fetch per
// dispatch (round-1 rocprof). BW-bound kernel needs no more than ~16 waves/CU.
// MODE 0: gsrc=xs   -> houts = h1*dinv[r]
// MODE 1: gsrc=h1s  -> houts = h2*dinv[r]
// MODE 2: gsrc=h2s  -> fout = (x + h1 + h2 + h3)/4 (h1,h2 rebuilt via sqrt(deg))
template <int MODE>
__global__ __launch_bounds__(256, 4) void k_layer(
    const int* __restrict__ row_ptr, const int* __restrict__ deg,
    const int* __restrict__ cols, const f16* __restrict__ gsrc,
    const void* __restrict__ xA, const void* __restrict__ xB, int split,
    const void* __restrict__ Wbase, int layer, const int* __restrict__ flags,
    const f16* __restrict__ h1s, const f16* __restrict__ h2s,
    f16* __restrict__ houts, float* __restrict__ fout, int N) {
  const int fw = flags[2];
  __shared__ float Wt[64 * 64];  // Wt[k*64 + d] = W[l][d][k]
  for (int i = threadIdx.x; i < 64 * 64; i += 256) {
    float wv = fw ? ((const float*)Wbase)[layer * 4096 + i]
                  : __bfloat162float(((const __hip_bfloat16*)Wbase)[layer * 4096 + i]);
    int d = i >> 6, k = i & 63;
    Wt[(k << 6) + d] = wv;
  }
  __syncthreads();

  const int wave = threadIdx.x >> 6;
  const int lane = threadIdx.x & 63;
  const int g = lane >> 3;  // edge-slot group 0..7
  const int t = lane & 7;   // dim chunk: dims 8t..8t+7
  const int stride = gridDim.x * 4;
  const f16* pb = gsrc + (t << 3);
  const int fu = flags[0], fi = flags[1];

  for (int r = blockIdx.x * 4 + wave; r < N; r += stride) {
    const int start = row_ptr[r];  // multiple of 4 (padded CSR)
    const int dr = deg[r];
    const int end = start + dr;
    const float dinv_r = rsqrtf((float)dr + 1e-10f);

    float sv[8] = {0.f, 0.f, 0.f, 0.f, 0.f, 0.f, 0.f, 0.f};

    int e = start;
    if (e + 32 <= end) {
      int4 c4 = *(const int4*)(cols + e + (g << 2));  // 16B aligned
      for (; e + 32 <= end;) {
        // prefetch next iteration's cols (stays inside the 64-int tail pad;
        // garbage indices are never dereferenced)
        int4 c4n = *(const int4*)(cols + e + 32 + (g << 2));
        half8 v0 = *(const half8*)(pb + ((size_t)c4.x << 6));
        half8 v1 = *(const half8*)(pb + ((size_t)c4.y << 6));
        half8 v2 = *(const half8*)(pb + ((size_t)c4.z << 6));
        half8 v3 = *(const half8*)(pb + ((size_t)c4.w << 6));
#pragma unroll
        for (int k = 0; k < 8; ++k)
          sv[k] += ((float)v0[k] + (float)v1[k]) + ((float)v2[k] + (float)v3[k]);
        e += 32;
        c4 = c4n;
      }
    }
    int rem = end - e;
    if (rem > 0) {
      // cols allocation is padded; values beyond `end` are loaded but never used
      int4 c4 = *(const int4*)(cols + e + (g << 2));
      int k0 = g << 2;
#pragma unroll
      for (int j = 0; j < 4; ++j) {
        int cj = (j == 0) ? c4.x : (j == 1) ? c4.y : (j == 2) ? c4.z : c4.w;
        if (k0 + j < rem) {
          half8 v = *(const half8*)(pb + ((size_t)cj << 6));
#pragma unroll
          for (int k = 0; k < 8; ++k) sv[k] += (float)v[k];
        }
      }
    }

    // reduce across the 8 edge groups (lanes with same t), then scale by dinv[r]
#pragma unroll
    for (int k = 0; k < 8; ++k) {
      float s = sv[k];
      s += __shfl_xor(s, 8);
      s += __shfl_xor(s, 16);
      s += __shfl_xor(s, 32);
      sv[k] = s * dinv_r;
    }

    // lin[d] = sum_k agg[k] * W[d][k]; dim k lives in lane (k>>3), elem (k&7)
    float lin = 0.f;
#pragma unroll
    for (int k = 0; k < 64; ++k) {
      float a = __shfl(sv[k & 7], k >> 3);
      lin += a * Wt[(k << 6) + lane];
    }
    float hn = lin > 0.f ? lin : 0.f;

    size_t o = (size_t)r * DIM + lane;
    if constexpr (MODE == 2) {
      float xr;
      if (r < split) {
        size_t ox = (size_t)r * DIM + lane;
        xr = fu ? ((const float*)xA)[ox]
                : __bfloat162float(((const __hip_bfloat16*)xA)[ox]);
      } else {
        size_t ox = (size_t)(r - split) * DIM + lane;
        xr = fi ? ((const float*)xB)[ox]
                : __bfloat162float(((const __hip_bfloat16*)xB)[ox]);
      }
      float sr = sqrtf((float)dr + 1e-10f);  // un-scale stored h1s/h2s
      float h1v = (float)h1s[o] * sr;
      float h2v = (float)h2s[o] * sr;
      fout[o] = (xr + h1v + h2v + hn) * 0.25f;  // FLOAT32 output
    } else {
      houts[o] = (f16)(hn * dinv_r);
    }
  }
}

extern "C" void kernel_launch(void* const* d_in, const int* in_sizes, int n_in,
                              void* d_out, int out_size, void* d_ws, size_t ws_size,
                              hipStream_t stream) {
  const void* user_e = d_in[0];
  const void* item_e = d_in[1];
  const void* W = d_in[2];
  const int* ui = (const int*)d_in[3];
  const int* ii = (const int*)d_in[4];

  const int NU = in_sizes[0] / DIM;
  const int NI = in_sizes[1] / DIM;
  const int N = NU + NI;
  const int E = in_sizes[3];
  float* out = (float*)d_out;  // OUTPUT IS FLOAT32

  // Workspace ~90 MB (N=150k, E=3M)
  auto align = [](size_t x) { return (x + 255) & ~(size_t)255; };
  char* w = (char*)d_ws;
  size_t off = 0;
  int* deg = (int*)(w + off);      off += align((size_t)N * 4);
  int* cnt = (int*)(w + off);      off += align((size_t)N * 4);
  int* bsum = (int*)(w + off);     off += align((size_t)4096 * 4);
  int* flags = (int*)(w + off);    off += align(256);
  size_t meta_zero_bytes = off;
  int* row_ptr = (int*)(w + off);  off += align((size_t)N * 4);
  float* dinv = (float*)(w + off); off += align((size_t)N * 4);
  // padded CSR: sum(ceil(deg/4)*4) <= 2E+3N, plus 64-int tail pad for int4 reads
  int* cols = (int*)(w + off);     off += align(((size_t)2 * E + 4 * (size_t)N + 64) * 4);
  f16* xs = (f16*)(w + off);       off += align((size_t)N * DIM * 2);
  f16* h1s = (f16*)(w + off);      off += align((size_t)N * DIM * 2);
  f16* h2s = (f16*)(w + off);      off += align((size_t)N * DIM * 2);
  (void)ws_size;

  hipMemsetAsync(d_ws, 0, meta_zero_bytes, stream);

  k_detect<<<1, 64, 0, stream>>>((const unsigned short*)user_e,
                                 (const unsigned short*)item_e,
                                 (const unsigned short*)W,
                                 (const unsigned int*)ui,
                                 (const unsigned int*)ii, flags);

  const int TPB = 256;
  k_degree<<<(E + TPB - 1) / TPB, TPB, 0, stream>>>(ui, ii, flags, deg, E, NU);
  k_dinv<<<(N + TPB - 1) / TPB, TPB, 0, stream>>>(deg, dinv, N);
  k_prescale<<<(N * (DIM / 4) + TPB - 1) / TPB, TPB, 0, stream>>>(
      user_e, item_e, NU, dinv, flags, xs, N);

  int nb = (N + 255) / 256;  // 586 for N=150000, must be <= 1024
  k_scan1<<<nb, 256, 0, stream>>>(deg, bsum, N);
  k_scan2<<<1, 1024, 0, stream>>>(bsum, nb);
  k_scan3<<<nb, 256, 0, stream>>>(deg, bsum, row_ptr, N);

  k_scatter<<<(E + TPB - 1) / TPB, TPB, 0, stream>>>(ui, ii, flags, row_ptr, cnt,
                                                     cols, E, NU);

  const int LGRID = 2048;
  k_layer<0><<<LGRID, 256, 0, stream>>>(row_ptr, deg, cols, xs, user_e, item_e, NU,
                                        W, 0, flags, nullptr, nullptr, h1s, nullptr, N);
  k_layer<1><<<LGRID, 256, 0, stream>>>(row_ptr, deg, cols, h1s, user_e, item_e, NU,
                                        W, 1, flags, nullptr, nullptr, h2s, nullptr, N);
  k_layer<2><<<LGRID, 256, 0, stream>>>(row_ptr, deg, cols, h2s, user_e, item_e, NU,
                                        W, 2, flags, h1s, h2s, nullptr, out, N);
}

// Round 3
// 1355.728 us; speedup vs baseline: 1.7399x; 1.0796x over previous
//
#include <hip/hip_runtime.h>
#include <hip/hip_bf16.h>

#define DIM 64

typedef _Float16 f16;
typedef _Float16 half8 __attribute__((ext_vector_type(8)));
typedef _Float16 half4 __attribute__((ext_vector_type(4)));

// ---------------- dtype detection ----------------
// flags: [0]=u_f32 [1]=i_f32 [2]=w_f32 [3]=ui_i64 [4]=ii_i64
__global__ void k_detect(const unsigned short* __restrict__ ue,
                         const unsigned short* __restrict__ ie,
                         const unsigned short* __restrict__ we,
                         const unsigned int* __restrict__ uidx,
                         const unsigned int* __restrict__ iidx,
                         int* __restrict__ flags) {
  if (threadIdx.x != 0 || blockIdx.x != 0) return;
  auto isf32 = [](const unsigned short* p) {
    for (int i = 0; i < 256; ++i)
      if (((p[i] >> 7) & 0xFF) >= 142) return 1;  // f32 mantissa garbage as bf16
    return 0;
  };
  auto is64 = [](const unsigned int* p) {
    for (int i = 0; i < 64; ++i)
      if (p[2 * i + 1] != 0u) return 0;
    return 1;
  };
  flags[0] = isf32(ue);
  flags[1] = isf32(ie);
  flags[2] = isf32(we);
  flags[3] = is64(uidx);
  flags[4] = is64(iidx);
}

__device__ __forceinline__ int load_idx(const int* p, int e, int f64) {
  return f64 ? (int)((const long long*)p)[e] : p[e];
}

// ---------------- degree ----------------
__global__ void k_degree(const int* __restrict__ ui, const int* __restrict__ ii,
                         const int* __restrict__ flags,
                         int* __restrict__ deg, int E, int NU) {
  int e = blockIdx.x * blockDim.x + threadIdx.x;
  if (e >= E) return;
  atomicAdd(&deg[load_idx(ui, e, flags[3])], 1);
  atomicAdd(&deg[NU + load_idx(ii, e, flags[4])], 1);
}

__global__ void k_dinv(const int* __restrict__ deg, float* __restrict__ dinv, int N) {
  int i = blockIdx.x * blockDim.x + threadIdx.x;
  if (i < N) dinv[i] = rsqrtf((float)deg[i] + 1e-10f);
}

// ---------------- prescale: xs[r][d] = fp16(dinv[r] * x[r][d]) ----------------
__global__ void k_prescale(const void* __restrict__ xA, const void* __restrict__ xB,
                           int split, const float* __restrict__ dinv,
                           const int* __restrict__ flags,
                           f16* __restrict__ xs, int N) {
  int i = blockIdx.x * blockDim.x + threadIdx.x;  // quad index
  int total = N * (DIM / 4);
  if (i >= total) return;
  int r = i >> 4;      // 16 quads per row
  int q = i & 15;
  const float dv = dinv[r];
  const int f = (r < split) ? flags[0] : flags[1];
  const void* base = (r < split) ? xA : xB;
  size_t o = (size_t)(r < split ? r : r - split) * DIM + (q << 2);
  float v0, v1, v2, v3;
  if (f) {
    float4 x4 = *(const float4*)((const float*)base + o);
    v0 = x4.x; v1 = x4.y; v2 = x4.z; v3 = x4.w;
  } else {
    ushort4 x4 = *(const ushort4*)((const unsigned short*)base + o);
    v0 = __uint_as_float((unsigned)x4.x << 16);
    v1 = __uint_as_float((unsigned)x4.y << 16);
    v2 = __uint_as_float((unsigned)x4.z << 16);
    v3 = __uint_as_float((unsigned)x4.w << 16);
  }
  half4 h;
  h[0] = (f16)(v0 * dv); h[1] = (f16)(v1 * dv);
  h[2] = (f16)(v2 * dv); h[3] = (f16)(v3 * dv);
  *(half4*)(xs + (size_t)r * DIM + (q << 2)) = h;
}

// ---------------- exclusive scan over PADDED degrees (3-phase) ----------------
__global__ void k_scan1(const int* __restrict__ deg, int* __restrict__ bsum, int N) {
  __shared__ int s[256];
  int i = blockIdx.x * 256 + threadIdx.x;
  s[threadIdx.x] = (i < N) ? ((deg[i] + 3) & ~3) : 0;
  __syncthreads();
  for (int off = 128; off > 0; off >>= 1) {
    if (threadIdx.x < off) s[threadIdx.x] += s[threadIdx.x + off];
    __syncthreads();
  }
  if (threadIdx.x == 0) bsum[blockIdx.x] = s[0];
}

__global__ void k_scan2(int* __restrict__ bsum, int nb) {
  __shared__ int s[1024];
  int t = threadIdx.x;
  int v = (t < nb) ? bsum[t] : 0;
  s[t] = v;
  __syncthreads();
  for (int off = 1; off < 1024; off <<= 1) {
    int tmp = (t >= off) ? s[t - off] : 0;
    __syncthreads();
    s[t] += tmp;
    __syncthreads();
  }
  if (t < nb) bsum[t] = s[t] - v;  // exclusive
}

__global__ void k_scan3(const int* __restrict__ deg, const int* __restrict__ bsum,
                        int* __restrict__ row_ptr, int N) {
  __shared__ int s[256];
  int t = threadIdx.x;
  int i = blockIdx.x * 256 + t;
  int v = (i < N) ? ((deg[i] + 3) & ~3) : 0;
  s[t] = v;
  __syncthreads();
  for (int off = 1; off < 256; off <<= 1) {
    int tmp = (t >= off) ? s[t - off] : 0;
    __syncthreads();
    s[t] += tmp;
    __syncthreads();
  }
  if (i < N) row_ptr[i] = bsum[blockIdx.x] + s[t] - v;
}

// ---------------- scatter edges into CSR (cols only), XCD-chunked ----------------
// Round-2 rocprof: flat scatter wrote 368 MB for a 24 MB cols array (15x ECC
// RMW amplification from partially-dirty lines) at 775 GB/s -> 475 us.
// Fix: partition rows into 8 chunks (~3 MB of cols each, fits one XCD's 4 MB
// write-back L2). Blocks with blockIdx%8==x handle chunk x only (consecutive
// blocks round-robin across XCDs), so each cols line fills completely while
// L2-resident and is evicted ONCE, full. Each group re-streams the edge list;
// the 48 MB index working set lives in the 256 MB LLC, so re-reads are cheap.
// Correctness does not depend on the blockIdx->XCD mapping.
__global__ __launch_bounds__(256) void k_scatter(
    const int* __restrict__ ui, const int* __restrict__ ii,
    const int* __restrict__ flags, const int* __restrict__ row_ptr,
    int* __restrict__ cnt, int* __restrict__ cols, int E, int NU, int N) {
  const int f3 = flags[3], f4 = flags[4];
  const int grp = blockIdx.x & 7;   // presumed XCD id
  const int gb = blockIdx.x >> 3;   // block index within group
  const int ngb = gridDim.x >> 3;   // blocks per group
  const int chunk = (N + 7) >> 3;
  const int rlo = grp * chunk;
  const int rhi = min(N, rlo + chunk);

  for (int e = gb * 256 + (int)threadIdx.x; e < E; e += ngb * 256) {
    int u = load_idx(ui, e, f3);
    int it = NU + load_idx(ii, e, f4);
    if (u >= rlo && u < rhi)
      cols[row_ptr[u] + atomicAdd(&cnt[u], 1)] = it;
    if (it >= rlo && it < rhi)
      cols[row_ptr[it] + atomicAdd(&cnt[it], 1)] = u;
  }
}

// ---------------- fused SpMM + Linear + ReLU ----------------
// gsrc is pre-scaled fp16 (dinv[c]*feat[c]); gather is pure sums.
// Wave layout: lane = 8*g + t; group g handles 4 contiguous edges per iter
// via one int4 cols load; lane t loads dims 8t..8t+7 as one 16B load.
// => 32 edges in flight per iteration, 5 vmem instructions.
// __launch_bounds__(256,4): 128-VGPR budget. (256,8) forced a 64-VGPR cap and
// SPILLED the loop working set -> 755 MB scratch writes (round-1 rocprof).
// MODE 0: gsrc=xs   -> houts = h1*dinv[r]
// MODE 1: gsrc=h1s  -> houts = h2*dinv[r]
// MODE 2: gsrc=h2s  -> fout = (x + h1 + h2 + h3)/4 (h1,h2 rebuilt via sqrt(deg))
template <int MODE>
__global__ __launch_bounds__(256, 4) void k_layer(
    const int* __restrict__ row_ptr, const int* __restrict__ deg,
    const int* __restrict__ cols, const f16* __restrict__ gsrc,
    const void* __restrict__ xA, const void* __restrict__ xB, int split,
    const void* __restrict__ Wbase, int layer, const int* __restrict__ flags,
    const f16* __restrict__ h1s, const f16* __restrict__ h2s,
    f16* __restrict__ houts, float* __restrict__ fout, int N) {
  const int fw = flags[2];
  __shared__ float Wt[64 * 64];  // Wt[k*64 + d] = W[l][d][k]
  for (int i = threadIdx.x; i < 64 * 64; i += 256) {
    float wv = fw ? ((const float*)Wbase)[layer * 4096 + i]
                  : __bfloat162float(((const __hip_bfloat16*)Wbase)[layer * 4096 + i]);
    int d = i >> 6, k = i & 63;
    Wt[(k << 6) + d] = wv;
  }
  __syncthreads();

  const int wave = threadIdx.x >> 6;
  const int lane = threadIdx.x & 63;
  const int g = lane >> 3;  // edge-slot group 0..7
  const int t = lane & 7;   // dim chunk: dims 8t..8t+7
  const int stride = gridDim.x * 4;
  const f16* pb = gsrc + (t << 3);
  const int fu = flags[0], fi = flags[1];

  for (int r = blockIdx.x * 4 + wave; r < N; r += stride) {
    const int start = row_ptr[r];  // multiple of 4 (padded CSR)
    const int dr = deg[r];
    const int end = start + dr;
    const float dinv_r = rsqrtf((float)dr + 1e-10f);

    float sv[8] = {0.f, 0.f, 0.f, 0.f, 0.f, 0.f, 0.f, 0.f};

    int e = start;
    if (e + 32 <= end) {
      int4 c4 = *(const int4*)(cols + e + (g << 2));  // 16B aligned
      for (; e + 32 <= end;) {
        // prefetch next iteration's cols (stays inside the 64-int tail pad;
        // garbage indices are never dereferenced)
        int4 c4n = *(const int4*)(cols + e + 32 + (g << 2));
        half8 v0 = *(const half8*)(pb + ((size_t)c4.x << 6));
        half8 v1 = *(const half8*)(pb + ((size_t)c4.y << 6));
        half8 v2 = *(const half8*)(pb + ((size_t)c4.z << 6));
        half8 v3 = *(const half8*)(pb + ((size_t)c4.w << 6));
#pragma unroll
        for (int k = 0; k < 8; ++k)
          sv[k] += ((float)v0[k] + (float)v1[k]) + ((float)v2[k] + (float)v3[k]);
        e += 32;
        c4 = c4n;
      }
    }
    int rem = end - e;
    if (rem > 0) {
      // cols allocation is padded; values beyond `end` are loaded but never used
      int4 c4 = *(const int4*)(cols + e + (g << 2));
      int k0 = g << 2;
#pragma unroll
      for (int j = 0; j < 4; ++j) {
        int cj = (j == 0) ? c4.x : (j == 1) ? c4.y : (j == 2) ? c4.z : c4.w;
        if (k0 + j < rem) {
          half8 v = *(const half8*)(pb + ((size_t)cj << 6));
#pragma unroll
          for (int k = 0; k < 8; ++k) sv[k] += (float)v[k];
        }
      }
    }

    // reduce across the 8 edge groups (lanes with same t), then scale by dinv[r]
#pragma unroll
    for (int k = 0; k < 8; ++k) {
      float s = sv[k];
      s += __shfl_xor(s, 8);
      s += __shfl_xor(s, 16);
      s += __shfl_xor(s, 32);
      sv[k] = s * dinv_r;
    }

    // lin[d] = sum_k agg[k] * W[d][k]; dim k lives in lane (k>>3), elem (k&7)
    float lin = 0.f;
#pragma unroll
    for (int k = 0; k < 64; ++k) {
      float a = __shfl(sv[k & 7], k >> 3);
      lin += a * Wt[(k << 6) + lane];
    }
    float hn = lin > 0.f ? lin : 0.f;

    size_t o = (size_t)r * DIM + lane;
    if constexpr (MODE == 2) {
      float xr;
      if (r < split) {
        size_t ox = (size_t)r * DIM + lane;
        xr = fu ? ((const float*)xA)[ox]
                : __bfloat162float(((const __hip_bfloat16*)xA)[ox]);
      } else {
        size_t ox = (size_t)(r - split) * DIM + lane;
        xr = fi ? ((const float*)xB)[ox]
                : __bfloat162float(((const __hip_bfloat16*)xB)[ox]);
      }
      float sr = sqrtf((float)dr + 1e-10f);  // un-scale stored h1s/h2s
      float h1v = (float)h1s[o] * sr;
      float h2v = (float)h2s[o] * sr;
      fout[o] = (xr + h1v + h2v + hn) * 0.25f;  // FLOAT32 output
    } else {
      houts[o] = (f16)(hn * dinv_r);
    }
  }
}

extern "C" void kernel_launch(void* const* d_in, const int* in_sizes, int n_in,
                              void* d_out, int out_size, void* d_ws, size_t ws_size,
                              hipStream_t stream) {
  const void* user_e = d_in[0];
  const void* item_e = d_in[1];
  const void* W = d_in[2];
  const int* ui = (const int*)d_in[3];
  const int* ii = (const int*)d_in[4];

  const int NU = in_sizes[0] / DIM;
  const int NI = in_sizes[1] / DIM;
  const int N = NU + NI;
  const int E = in_sizes[3];
  float* out = (float*)d_out;  // OUTPUT IS FLOAT32

  // Workspace ~90 MB (N=150k, E=3M)
  auto align = [](size_t x) { return (x + 255) & ~(size_t)255; };
  char* w = (char*)d_ws;
  size_t off = 0;
  int* deg = (int*)(w + off);      off += align((size_t)N * 4);
  int* cnt = (int*)(w + off);      off += align((size_t)N * 4);
  int* bsum = (int*)(w + off);     off += align((size_t)4096 * 4);
  int* flags = (int*)(w + off);    off += align(256);
  size_t meta_zero_bytes = off;
  int* row_ptr = (int*)(w + off);  off += align((size_t)N * 4);
  float* dinv = (float*)(w + off); off += align((size_t)N * 4);
  // padded CSR: sum(ceil(deg/4)*4) <= 2E+3N, plus 64-int tail pad for int4 reads
  int* cols = (int*)(w + off);     off += align(((size_t)2 * E + 4 * (size_t)N + 64) * 4);
  f16* xs = (f16*)(w + off);       off += align((size_t)N * DIM * 2);
  f16* h1s = (f16*)(w + off);      off += align((size_t)N * DIM * 2);
  f16* h2s = (f16*)(w + off);      off += align((size_t)N * DIM * 2);
  (void)ws_size;

  hipMemsetAsync(d_ws, 0, meta_zero_bytes, stream);

  k_detect<<<1, 64, 0, stream>>>((const unsigned short*)user_e,
                                 (const unsigned short*)item_e,
                                 (const unsigned short*)W,
                                 (const unsigned int*)ui,
                                 (const unsigned int*)ii, flags);

  const int TPB = 256;
  k_degree<<<(E + TPB - 1) / TPB, TPB, 0, stream>>>(ui, ii, flags, deg, E, NU);
  k_dinv<<<(N + TPB - 1) / TPB, TPB, 0, stream>>>(deg, dinv, N);
  k_prescale<<<(N * (DIM / 4) + TPB - 1) / TPB, TPB, 0, stream>>>(
      user_e, item_e, NU, dinv, flags, xs, N);

  int nb = (N + 255) / 256;  // 586 for N=150000, must be <= 1024
  k_scan1<<<nb, 256, 0, stream>>>(deg, bsum, N);
  k_scan2<<<1, 1024, 0, stream>>>(bsum, nb);
  k_scan3<<<nb, 256, 0, stream>>>(deg, bsum, row_ptr, N);

  k_scatter<<<2048, 256, 0, stream>>>(ui, ii, flags, row_ptr, cnt, cols, E, NU, N);

  const int LGRID = 2048;
  k_layer<0><<<LGRID, 256, 0, stream>>>(row_ptr, deg, cols, xs, user_e, item_e, NU,
                                        W, 0, flags, nullptr, nullptr, h1s, nullptr, N);
  k_layer<1><<<LGRID, 256, 0, stream>>>(row_ptr, deg, cols, h1s, user_e, item_e, NU,
                                        W, 1, flags, nullptr, nullptr, h2s, nullptr, N);
  k_layer<2><<<LGRID, 256, 0, stream>>>(row_ptr, deg, cols, h2s, user_e, item_e, NU,
                                        W, 2, flags, h1s, h2s, nullptr, out, N);
}

// Round 4
// 1259.149 us; speedup vs baseline: 1.8733x; 1.0767x over previous
//
#include <hip/hip_runtime.h>
#include <hip/hip_bf16.h>

#define DIM 64

typedef _Float16 f16;
typedef _Float16 half8 __attribute__((ext_vector_type(8)));
typedef _Float16 half4 __attribute__((ext_vector_type(4)));

// ---------------- dtype detection ----------------
// flags: [0]=u_f32 [1]=i_f32 [2]=w_f32 [3]=ui_i64 [4]=ii_i64
__global__ void k_detect(const unsigned short* __restrict__ ue,
                         const unsigned short* __restrict__ ie,
                         const unsigned short* __restrict__ we,
                         const unsigned int* __restrict__ uidx,
                         const unsigned int* __restrict__ iidx,
                         int* __restrict__ flags) {
  if (threadIdx.x != 0 || blockIdx.x != 0) return;
  auto isf32 = [](const unsigned short* p) {
    for (int i = 0; i < 256; ++i)
      if (((p[i] >> 7) & 0xFF) >= 142) return 1;  // f32 mantissa garbage as bf16
    return 0;
  };
  auto is64 = [](const unsigned int* p) {
    for (int i = 0; i < 64; ++i)
      if (p[2 * i + 1] != 0u) return 0;
    return 1;
  };
  flags[0] = isf32(ue);
  flags[1] = isf32(ie);
  flags[2] = isf32(we);
  flags[3] = is64(uidx);
  flags[4] = is64(iidx);
}

__device__ __forceinline__ int load_idx(const int* p, int e, int f64) {
  return f64 ? (int)((const long long*)p)[e] : p[e];
}

// ---------------- degree ----------------
__global__ void k_degree(const int* __restrict__ ui, const int* __restrict__ ii,
                         const int* __restrict__ flags,
                         int* __restrict__ deg, int E, int NU) {
  int e = blockIdx.x * blockDim.x + threadIdx.x;
  if (e >= E) return;
  atomicAdd(&deg[load_idx(ui, e, flags[3])], 1);
  atomicAdd(&deg[NU + load_idx(ii, e, flags[4])], 1);
}

__global__ void k_dinv(const int* __restrict__ deg, float* __restrict__ dinv, int N) {
  int i = blockIdx.x * blockDim.x + threadIdx.x;
  if (i < N) dinv[i] = rsqrtf((float)deg[i] + 1e-10f);
}

// ---------------- prescale: xs[r][d] = fp16(dinv[r] * x[r][d]) ----------------
__global__ void k_prescale(const void* __restrict__ xA, const void* __restrict__ xB,
                           int split, const float* __restrict__ dinv,
                           const int* __restrict__ flags,
                           f16* __restrict__ xs, int N) {
  int i = blockIdx.x * blockDim.x + threadIdx.x;  // quad index
  int total = N * (DIM / 4);
  if (i >= total) return;
  int r = i >> 4;      // 16 quads per row
  int q = i & 15;
  const float dv = dinv[r];
  const int f = (r < split) ? flags[0] : flags[1];
  const void* base = (r < split) ? xA : xB;
  size_t o = (size_t)(r < split ? r : r - split) * DIM + (q << 2);
  float v0, v1, v2, v3;
  if (f) {
    float4 x4 = *(const float4*)((const float*)base + o);
    v0 = x4.x; v1 = x4.y; v2 = x4.z; v3 = x4.w;
  } else {
    ushort4 x4 = *(const ushort4*)((const unsigned short*)base + o);
    v0 = __uint_as_float((unsigned)x4.x << 16);
    v1 = __uint_as_float((unsigned)x4.y << 16);
    v2 = __uint_as_float((unsigned)x4.z << 16);
    v3 = __uint_as_float((unsigned)x4.w << 16);
  }
  half4 h;
  h[0] = (f16)(v0 * dv); h[1] = (f16)(v1 * dv);
  h[2] = (f16)(v2 * dv); h[3] = (f16)(v3 * dv);
  *(half4*)(xs + (size_t)r * DIM + (q << 2)) = h;
}

// ---------------- exclusive scan over PADDED degrees (3-phase) ----------------
__global__ void k_scan1(const int* __restrict__ deg, int* __restrict__ bsum, int N) {
  __shared__ int s[256];
  int i = blockIdx.x * 256 + threadIdx.x;
  s[threadIdx.x] = (i < N) ? ((deg[i] + 3) & ~3) : 0;
  __syncthreads();
  for (int off = 128; off > 0; off >>= 1) {
    if (threadIdx.x < off) s[threadIdx.x] += s[threadIdx.x + off];
    __syncthreads();
  }
  if (threadIdx.x == 0) bsum[blockIdx.x] = s[0];
}

__global__ void k_scan2(int* __restrict__ bsum, int nb) {
  __shared__ int s[1024];
  int t = threadIdx.x;
  int v = (t < nb) ? bsum[t] : 0;
  s[t] = v;
  __syncthreads();
  for (int off = 1; off < 1024; off <<= 1) {
    int tmp = (t >= off) ? s[t - off] : 0;
    __syncthreads();
    s[t] += tmp;
    __syncthreads();
  }
  if (t < nb) bsum[t] = s[t] - v;  // exclusive
}

__global__ void k_scan3(const int* __restrict__ deg, const int* __restrict__ bsum,
                        int* __restrict__ row_ptr, int N) {
  __shared__ int s[256];
  int t = threadIdx.x;
  int i = blockIdx.x * 256 + t;
  int v = (i < N) ? ((deg[i] + 3) & ~3) : 0;
  s[t] = v;
  __syncthreads();
  for (int off = 1; off < 256; off <<= 1) {
    int tmp = (t >= off) ? s[t - off] : 0;
    __syncthreads();
    s[t] += tmp;
    __syncthreads();
  }
  if (i < N) row_ptr[i] = bsum[blockIdx.x] + s[t] - v;
}

// ---------------- scatter edges into CSR (cols only), XCD-chunked ----------------
// (round-3 version: each blockIdx%8 group owns an ~3 MB cols chunk so lines
// fill while L2-resident; fixed the 15x ECC-RMW write amplification.)
__global__ __launch_bounds__(256) void k_scatter(
    const int* __restrict__ ui, const int* __restrict__ ii,
    const int* __restrict__ flags, const int* __restrict__ row_ptr,
    int* __restrict__ cnt, int* __restrict__ cols, int E, int NU, int N) {
  const int f3 = flags[3], f4 = flags[4];
  const int grp = blockIdx.x & 7;   // presumed XCD id
  const int gb = blockIdx.x >> 3;   // block index within group
  const int ngb = gridDim.x >> 3;   // blocks per group
  const int chunk = (N + 7) >> 3;
  const int rlo = grp * chunk;
  const int rhi = min(N, rlo + chunk);

  for (int e = gb * 256 + (int)threadIdx.x; e < E; e += ngb * 256) {
    int u = load_idx(ui, e, f3);
    int it = NU + load_idx(ii, e, f4);
    if (u >= rlo && u < rhi)
      cols[row_ptr[u] + atomicAdd(&cnt[u], 1)] = it;
    if (it >= rlo && it < rhi)
      cols[row_ptr[it] + atomicAdd(&cnt[it], 1)] = u;
  }
}

// ---------------- pure gather: agg[r][:] = sum_{c in N(r)} gsrc[c][:] ----------------
// Round-3 rocprof: fused gather+Linear ran at 2.6 TB/s, occupancy 44%, all
// pipes <33% -> latency-bound (round-1 proved the fabric does 4.4 TB/s).
// The per-row 400-cycle serial Linear starved the memory pipeline. This
// kernel is gathers only: no LDS, no launch-bounds cap, ~50 VGPR -> 8
// waves/SIMD, rows flow back-to-back issuing loads.
// Wave layout: lane = 8*g + t; group g does 4 edges/iter via one int4 cols
// load; lane t covers dims 8t..8t+7 as one 16B load. dinv_r applied later
// (linear in W commutes).
__global__ __launch_bounds__(256) void k_gather(
    const int* __restrict__ row_ptr, const int* __restrict__ deg,
    const int* __restrict__ cols, const f16* __restrict__ gsrc,
    float* __restrict__ agg, int N) {
  const int wave = threadIdx.x >> 6;
  const int lane = threadIdx.x & 63;
  const int g = lane >> 3;  // edge-slot group 0..7
  const int t = lane & 7;   // dim chunk: dims 8t..8t+7
  const int stride = gridDim.x * 4;
  const f16* pb = gsrc + (t << 3);

  for (int r = blockIdx.x * 4 + wave; r < N; r += stride) {
    const int start = row_ptr[r];  // multiple of 4 (padded CSR)
    const int end = start + deg[r];

    float sv[8] = {0.f, 0.f, 0.f, 0.f, 0.f, 0.f, 0.f, 0.f};

    int e = start;
    if (e + 32 <= end) {
      int4 c4 = *(const int4*)(cols + e + (g << 2));  // 16B aligned
      for (; e + 32 <= end;) {
        // prefetch next iteration's cols (stays inside padded allocation;
        // garbage indices are never dereferenced)
        int4 c4n = *(const int4*)(cols + e + 32 + (g << 2));
        half8 v0 = *(const half8*)(pb + ((size_t)c4.x << 6));
        half8 v1 = *(const half8*)(pb + ((size_t)c4.y << 6));
        half8 v2 = *(const half8*)(pb + ((size_t)c4.z << 6));
        half8 v3 = *(const half8*)(pb + ((size_t)c4.w << 6));
#pragma unroll
        for (int k = 0; k < 8; ++k)
          sv[k] += ((float)v0[k] + (float)v1[k]) + ((float)v2[k] + (float)v3[k]);
        e += 32;
        c4 = c4n;
      }
    }
    int rem = end - e;
    if (rem > 0) {
      // cols allocation is padded; values beyond `end` are loaded but never used
      int4 c4 = *(const int4*)(cols + e + (g << 2));
      int k0 = g << 2;
#pragma unroll
      for (int j = 0; j < 4; ++j) {
        int cj = (j == 0) ? c4.x : (j == 1) ? c4.y : (j == 2) ? c4.z : c4.w;
        if (k0 + j < rem) {
          half8 v = *(const half8*)(pb + ((size_t)cj << 6));
#pragma unroll
          for (int k = 0; k < 8; ++k) sv[k] += (float)v[k];
        }
      }
    }

    // butterfly over the 8 edge groups -> every lane holds the full sums
#pragma unroll
    for (int k = 0; k < 8; ++k) {
      float s = sv[k];
      s += __shfl_xor(s, 8);
      s += __shfl_xor(s, 16);
      s += __shfl_xor(s, 32);
      sv[k] = s;
    }

    // lane (g,t) writes dim t*8+g with value sv[g]  (static-index select chain)
    float v = sv[0];
#pragma unroll
    for (int j = 1; j < 8; ++j) v = (g == j) ? sv[j] : v;
    agg[(size_t)r * DIM + (t << 3) + g] = v;
  }
}

// ---------------- streaming Linear + ReLU (+ final combine) ----------------
// lane = output dim d; W row d held in 64 VGPRs (full unroll, static index);
// agg row broadcast via readlane. ~2 VALU instr per FMA, fully streaming.
// MODE 0: houts = f16(dinv_r * relu(dinv_r * agg W^T))   (pre-scaled h1s)
// MODE 1: same -> h2s
// MODE 2: fout = (x + h1 + h2 + h3)/4, h1/h2 rebuilt via sqrt(deg)
template <int MODE>
__global__ __launch_bounds__(256) void k_linear(
    const float* __restrict__ agg, const int* __restrict__ deg,
    const void* __restrict__ Wbase, int layer, const int* __restrict__ flags,
    const void* __restrict__ xA, const void* __restrict__ xB, int split,
    const f16* __restrict__ h1s, const f16* __restrict__ h2s,
    f16* __restrict__ houts, float* __restrict__ fout, int N) {
  const int fw = flags[2];
  __shared__ float Wt[64 * 64];  // Wt[k*64 + d] = W[l][d][k]
  for (int i = threadIdx.x; i < 64 * 64; i += 256) {
    float wv = fw ? ((const float*)Wbase)[layer * 4096 + i]
                  : __bfloat162float(((const __hip_bfloat16*)Wbase)[layer * 4096 + i]);
    int d = i >> 6, k = i & 63;
    Wt[(k << 6) + d] = wv;
  }
  __syncthreads();

  const int wave = threadIdx.x >> 6;
  const int lane = threadIdx.x & 63;  // = output dim d

  float w[64];  // W[d][k] for this lane's d, k = 0..63 (static indices only)
#pragma unroll
  for (int k = 0; k < 64; ++k) w[k] = Wt[(k << 6) + lane];

  const int fu = flags[0], fi = flags[1];
  const int stride = gridDim.x * 4;

  for (int r = blockIdx.x * 4 + wave; r < N; r += stride) {
    float a = agg[(size_t)r * DIM + lane];
    float lin = 0.f;
#pragma unroll
    for (int k = 0; k < 64; ++k) lin += __shfl(a, k) * w[k];

    const int dr = deg[r];
    const float dinv_r = rsqrtf((float)dr + 1e-10f);
    float hn = lin * dinv_r;
    hn = hn > 0.f ? hn : 0.f;

    size_t o = (size_t)r * DIM + lane;
    if constexpr (MODE == 2) {
      float xr;
      if (r < split) {
        size_t ox = (size_t)r * DIM + lane;
        xr = fu ? ((const float*)xA)[ox]
                : __bfloat162float(((const __hip_bfloat16*)xA)[ox]);
      } else {
        size_t ox = (size_t)(r - split) * DIM + lane;
        xr = fi ? ((const float*)xB)[ox]
                : __bfloat162float(((const __hip_bfloat16*)xB)[ox]);
      }
      float sr = sqrtf((float)dr + 1e-10f);  // un-scale stored h1s/h2s
      float h1v = (float)h1s[o] * sr;
      float h2v = (float)h2s[o] * sr;
      fout[o] = (xr + h1v + h2v + hn) * 0.25f;  // FLOAT32 output
    } else {
      houts[o] = (f16)(hn * dinv_r);
    }
  }
}

extern "C" void kernel_launch(void* const* d_in, const int* in_sizes, int n_in,
                              void* d_out, int out_size, void* d_ws, size_t ws_size,
                              hipStream_t stream) {
  const void* user_e = d_in[0];
  const void* item_e = d_in[1];
  const void* W = d_in[2];
  const int* ui = (const int*)d_in[3];
  const int* ii = (const int*)d_in[4];

  const int NU = in_sizes[0] / DIM;
  const int NI = in_sizes[1] / DIM;
  const int N = NU + NI;
  const int E = in_sizes[3];
  float* out = (float*)d_out;  // OUTPUT IS FLOAT32

  // Workspace ~128 MB (N=150k, E=3M)
  auto align = [](size_t x) { return (x + 255) & ~(size_t)255; };
  char* w = (char*)d_ws;
  size_t off = 0;
  int* deg = (int*)(w + off);      off += align((size_t)N * 4);
  int* cnt = (int*)(w + off);      off += align((size_t)N * 4);
  int* bsum = (int*)(w + off);     off += align((size_t)4096 * 4);
  int* flags = (int*)(w + off);    off += align(256);
  size_t meta_zero_bytes = off;
  int* row_ptr = (int*)(w + off);  off += align((size_t)N * 4);
  float* dinv = (float*)(w + off); off += align((size_t)N * 4);
  // padded CSR: sum(ceil(deg/4)*4) <= 2E+3N, plus 64-int tail pad for int4 reads
  int* cols = (int*)(w + off);     off += align(((size_t)2 * E + 4 * (size_t)N + 64) * 4);
  f16* xs = (f16*)(w + off);       off += align((size_t)N * DIM * 2);
  f16* h1s = (f16*)(w + off);      off += align((size_t)N * DIM * 2);
  f16* h2s = (f16*)(w + off);      off += align((size_t)N * DIM * 2);
  float* agg = (float*)(w + off);  off += align((size_t)N * DIM * 4);
  (void)ws_size;

  hipMemsetAsync(d_ws, 0, meta_zero_bytes, stream);

  k_detect<<<1, 64, 0, stream>>>((const unsigned short*)user_e,
                                 (const unsigned short*)item_e,
                                 (const unsigned short*)W,
                                 (const unsigned int*)ui,
                                 (const unsigned int*)ii, flags);

  const int TPB = 256;
  k_degree<<<(E + TPB - 1) / TPB, TPB, 0, stream>>>(ui, ii, flags, deg, E, NU);
  k_dinv<<<(N + TPB - 1) / TPB, TPB, 0, stream>>>(deg, dinv, N);
  k_prescale<<<(N * (DIM / 4) + TPB - 1) / TPB, TPB, 0, stream>>>(
      user_e, item_e, NU, dinv, flags, xs, N);

  int nb = (N + 255) / 256;  // 586 for N=150000, must be <= 1024
  k_scan1<<<nb, 256, 0, stream>>>(deg, bsum, N);
  k_scan2<<<1, 1024, 0, stream>>>(bsum, nb);
  k_scan3<<<nb, 256, 0, stream>>>(deg, bsum, row_ptr, N);

  k_scatter<<<2048, 256, 0, stream>>>(ui, ii, flags, row_ptr, cnt, cols, E, NU, N);

  const int GGRID = 4096;  // gather: fine-grained for load balance + full residency
  const int LGRID = 2048;

  k_gather<<<GGRID, 256, 0, stream>>>(row_ptr, deg, cols, xs, agg, N);
  k_linear<0><<<LGRID, 256, 0, stream>>>(agg, deg, W, 0, flags, user_e, item_e, NU,
                                         nullptr, nullptr, h1s, nullptr, N);
  k_gather<<<GGRID, 256, 0, stream>>>(row_ptr, deg, cols, h1s, agg, N);
  k_linear<1><<<LGRID, 256, 0, stream>>>(agg, deg, W, 1, flags, user_e, item_e, NU,
                                         nullptr, nullptr, h2s, nullptr, N);
  k_gather<<<GGRID, 256, 0, stream>>>(row_ptr, deg, cols, h2s, agg, N);
  k_linear<2><<<LGRID, 256, 0, stream>>>(agg, deg, W, 2, flags, user_e, item_e, NU,
                                         h1s, h2s, nullptr, out, N);
}